// Round 8
// baseline (110.174 us; speedup 1.0000x reference)
//
#include <hip/hip_runtime.h>
#include <hip/hip_bf16.h>

#define BS 128
#define T 256
#define D 1024
#define NCAT 2688
#define NFEAT 1024

typedef short bf16x8 __attribute__((ext_vector_type(8)));
typedef float f32x4 __attribute__((ext_vector_type(4)));
typedef unsigned short u16;
typedef u16 u16x4 __attribute__((ext_vector_type(4)));

__device__ __forceinline__ u16 f2bf(float f) {
    unsigned int u = __float_as_uint(f);
    u += 0x7fffu + ((u >> 16) & 1u);   // round-to-nearest-even
    return (u16)(u >> 16);
}

// hw bf16 convert (compiler emits v_cvt_pk_bf16_f32; RNE, same as f2bf)
__device__ __forceinline__ short fb(float x) {
    __hip_bfloat16 h = __float2bfloat16(x);
    union { __hip_bfloat16 h; short s; } u; u.h = h; return u.s;
}
__device__ __forceinline__ bf16x8 cvt8(const float* __restrict__ p) {
    f32x4 a = *(const f32x4*)p;
    f32x4 b = *(const f32x4*)(p + 4);
    bf16x8 r;
    r[0] = fb(a[0]); r[1] = fb(a[1]); r[2] = fb(a[2]); r[3] = fb(a[3]);
    r[4] = fb(b[0]); r[5] = fb(b[1]); r[6] = fb(b[2]); r[7] = fb(b[3]);
    return r;
}

// ---------------------------------------------------------------------------
// ka: 1024 blocks. Each block: (1) converts its 928-float4 slice of W1/W2/W4
//     to bf16 (inline — no separate convert blocks, no post-stream tail);
//     (2) mask-reduce for vl/s/e; (3) copies its 32 rows of visual_fea
//     (fixed-bound loop -> full unroll, deep MLP) while accumulating
//     masked-mean and segment partial sums.
// ---------------------------------------------------------------------------
__global__ __launch_bounds__(256, 4)
void ka(const float* __restrict__ vf, float* __restrict__ out0,
        const int* __restrict__ vmask, const float* __restrict__ loc,
        const float* __restrict__ W1, const float* __restrict__ W2,
        const float* __restrict__ W4,
        u16* __restrict__ W1b, u16* __restrict__ W2b, u16* __restrict__ W4b,
        float* __restrict__ pgv, float* __restrict__ pseg) {
    int blk = blockIdx.x, tid = threadIdx.x;

    // ---- inline weight conversion: float4 indices [blk*928, blk*928+928) ----
    {
        int base = blk * 928;                 // 1024 * 928 = 950272 total
#pragma unroll
        for (int rpt = 0; rpt < 4; ++rpt) {
            int local = rpt * 256 + tid;
            if (local < 928) {
                int i = base + local;
                const float* src; u16* dst;
                if (i < 131072)      { src = W1 + 4 * i;            dst = W1b + 4 * i; }
                else if (i < 262144) { src = W2 + 4 * (i - 131072); dst = W2b + 4 * (i - 131072); }
                else                 { src = W4 + 4 * (i - 262144); dst = W4b + 4 * (i - 262144); }
                f32x4 v = *(const f32x4*)src;
                u16x4 o;
                o[0] = f2bf(v[0]); o[1] = f2bf(v[1]); o[2] = f2bf(v[2]); o[3] = f2bf(v[3]);
                *(u16x4*)dst = o;
            }
        }
    }

    // ---- vl / s / e ----
    int b = blk >> 3, tc = blk & 7;
    __shared__ int red[256];
    __shared__ int sse[3];
    red[tid] = vmask[b * T + tid];
    __syncthreads();
    for (int off = 128; off > 0; off >>= 1) {
        if (tid < off) red[tid] += red[tid + off];
        __syncthreads();
    }
    if (tid == 0) {
        int vl = red[0];
        float sc = (float)(vl - 1);
        sse[0] = vl;
        sse[1] = (int)floorf(loc[2 * b] * sc);
        sse[2] = (int)floorf(loc[2 * b + 1] * sc);
    }
    __syncthreads();
    int vl = sse[0], s = sse[1], e = sse[2];

    // ---- copy + pool, fixed 32-iteration loop ----
    int t0 = tc * 32;
    int d0 = tid * 4;
    f32x4 g  = {0.f, 0.f, 0.f, 0.f};
    f32x4 sg = {0.f, 0.f, 0.f, 0.f};
    const float* src = vf   + ((size_t)(b * T + t0)) * D + d0;
    float*       dst = out0 + ((size_t)(b * T + t0)) * D + d0;
    for (int i = 0; i < 32; ++i) {
        f32x4 v = *(const f32x4*)src;
        __builtin_nontemporal_store(v, (f32x4*)dst);
        int t = t0 + i;
        if (t < vl) g += v;
        if (t >= s && t <= e) sg += v;
        src += D; dst += D;
    }
    int o = (b * 8 + tc) * D + d0;
    *(f32x4*)(pgv  + o) = g;
    *(f32x4*)(pseg + o) = sg;
}

// ---------------------------------------------------------------------------
// kB: ONE launch, two independent roles (no intra-kernel dependency):
//  blocks [0,128):  k2 — reduce partials -> cat[gv], sen -> cat+out1, loc head.
//  blocks [128,256): k3 — vs = relu((lv@W1^T+b1)*(sen@W2^T+b2)) -> cat[vs],
//    WITHOUT needing k2's lv: lv@W1^T == lvscale_m * sum_c (pseg_c @ W1^T),
//    GEMM with K=8192 over f32 partials, bf16-converted on the fly.
//    vl/s/e recomputed per block from vmask. Zero atomics.
// cat layout: [sen 0..1023 | gv 1024..2047 | vs 2048..2559 | loc 2560..2687]
// ---------------------------------------------------------------------------
__global__ void kB(const float* __restrict__ sen_fea, const float* __restrict__ loc,
                   const float* __restrict__ W3, const float* __restrict__ b3,
                   const int* __restrict__ vmask,
                   const float* __restrict__ pgv, const float* __restrict__ pseg,
                   const u16* __restrict__ W1b, const float* __restrict__ b1,
                   const u16* __restrict__ W2b, const float* __restrict__ b2,
                   u16* __restrict__ cat, float* __restrict__ out1) {
    int blk = blockIdx.x, tid = threadIdx.x;

    __shared__ int   red[256];
    __shared__ int   sse[3];
    __shared__ int   mred[16][16];
    __shared__ float lvscale[16];
    __shared__ float p2s[2][4][64];
    __shared__ float qs[2][4][64];

    if (blk < 128) {
        // ---------------- k2 ----------------
        int b = blk;
        red[tid] = vmask[b * T + tid];
        __syncthreads();
        for (int off = 128; off > 0; off >>= 1) {
            if (tid < off) red[tid] += red[tid + off];
            __syncthreads();
        }
        if (tid == 0) {
            int vl = red[0];
            float sc = (float)(vl - 1);
            sse[0] = vl;
            sse[1] = (int)floorf(loc[2 * b] * sc);
            sse[2] = (int)floorf(loc[2 * b + 1] * sc);
        }
        __syncthreads();
        int vl = sse[0];
        float inv_vl = 1.0f / (float)vl;

        for (int d = tid; d < D; d += 256) {
            float gs = 0.f;
#pragma unroll
            for (int c = 0; c < 8; ++c) gs += pgv[(b * 8 + c) * D + d];
            cat[b * NCAT + 1024 + d] = f2bf(gs * inv_vl);
            float sf = sen_fea[b * D + d];
            cat[b * NCAT + d] = f2bf(sf);
            out1[b * D + d] = sf;
        }
        if (tid < 128) {
            float v = loc[2 * b] * W3[2 * tid] + loc[2 * b + 1] * W3[2 * tid + 1] + b3[tid];
            cat[b * NCAT + 2560 + tid] = f2bf(fmaxf(v, 0.f));
        }
        return;
    }

    // ---------------- k3 (self-served) ----------------
    int bi = blk - 128;
    int mt = bi >> 4, ntg = bi & 15;     // 8 m-tiles x 16 col-groups of 32
    int m0g = mt * 16;

    // per-batch lvscale for the 16 rows of this m-tile
    int j = tid >> 4, part = tid & 15;
    int macc = 0;
#pragma unroll
    for (int q = 0; q < 16; ++q) macc += vmask[(m0g + j) * T + part * 16 + q];
    mred[j][part] = macc;
    __syncthreads();
    if (part == 0) {
        int vl = 0;
#pragma unroll
        for (int q = 0; q < 16; ++q) vl += mred[j][q];
        float sc = (float)(vl - 1);
        int s = (int)floorf(loc[2 * (m0g + j)] * sc);
        int e = (int)floorf(loc[2 * (m0g + j) + 1] * sc);
        int cnt = e + 1 - s; if (cnt < 1) cnt = 1;
        lvscale[j] = (s <= e) ? (1.0f / (float)cnt) : 0.f;
    }
    // (lvscale read only after the post-GEMM __syncthreads)

    int wid = tid >> 6, lane = tid & 63;
    int sub = wid & 1, role = wid >> 1;   // role 0: P c=0..3 + final; role 1: P c=4..7 + Q
    int n0 = ntg * 32 + sub * 16;
    int row = lane & 15, kg = lane >> 4;

    f32x4 accP = {0.f, 0.f, 0.f, 0.f};
    const float* paP = pseg + ((size_t)((m0g + row) * 8 + role * 4)) * D + kg * 8;
    const u16*  pbP = W1b + (n0 + row) * D + kg * 8;
#pragma unroll
    for (int c = 0; c < 4; ++c)
        for (int k = 0; k < 1024; k += 32)
            accP = __builtin_amdgcn_mfma_f32_16x16x32_bf16(
                cvt8(paP + c * D + k), *(const bf16x8*)(pbP + k), accP, 0, 0, 0);

    int col = lane & 15, rbase = (lane >> 4) * 4;
    if (role == 1) {
        f32x4 accQ = {0.f, 0.f, 0.f, 0.f};
        const float* paQ = sen_fea + (m0g + row) * D + kg * 8;
        const u16*  pbQ = W2b + (n0 + row) * D + kg * 8;
        for (int k = 0; k < 1024; k += 32)
            accQ = __builtin_amdgcn_mfma_f32_16x16x32_bf16(
                cvt8(paQ + k), *(const bf16x8*)(pbQ + k), accQ, 0, 0, 0);
        float bb2 = b2[n0 + col];
#pragma unroll
        for (int r = 0; r < 4; ++r) {
            p2s[sub][r][lane] = accP[r];
            qs[sub][r][lane]  = accQ[r] + bb2;
        }
    }
    __syncthreads();
    if (role == 0) {
        float bb1 = b1[n0 + col];
#pragma unroll
        for (int r = 0; r < 4; ++r) {
            float P = (accP[r] + p2s[sub][r][lane]) * lvscale[rbase + r] + bb1;
            cat[(m0g + rbase + r) * NCAT + 2048 + n0 + col] =
                f2bf(fmaxf(P * qs[sub][r][lane], 0.f));
        }
    }
}

// ---------------------------------------------------------------------------
// kD: k4 feature GEMM — out2 = relu(cat @ W4^T + b4). M=128,N=1024,K=2688.
// 512 blocks x 4 waves, split-K=4 (672 each), LDS reduce.
// ---------------------------------------------------------------------------
__global__ void kD(const u16* __restrict__ cat, const u16* __restrict__ W4b,
                   const float* __restrict__ b4, float* __restrict__ out2) {
    int blk = blockIdx.x, tid = threadIdx.x;
    __shared__ float qsf[3][4][64];

    int mt = blk >> 6, nt = blk & 63;
    int wid = tid >> 6, lane = tid & 63;
    int m0 = mt * 16, n0 = nt * 16;
    int row = lane & 15, kg = lane >> 4;

    const u16* pa = cat + (m0 + row) * NCAT + wid * 672 + kg * 8;
    const u16* pb = W4b + (n0 + row) * NCAT + wid * 672 + kg * 8;

    f32x4 acc = {0.f, 0.f, 0.f, 0.f};
    for (int k = 0; k < 672; k += 32)
        acc = __builtin_amdgcn_mfma_f32_16x16x32_bf16(*(const bf16x8*)(pa + k),
                                                      *(const bf16x8*)(pb + k), acc, 0, 0, 0);
    int col = lane & 15, rbase = (lane >> 4) * 4;
    if (wid) {
#pragma unroll
        for (int r = 0; r < 4; ++r) qsf[wid - 1][r][lane] = acc[r];
    }
    __syncthreads();
    if (wid == 0) {
        float bb = b4[n0 + col];
#pragma unroll
        for (int r = 0; r < 4; ++r) {
            float v = acc[r] + qsf[0][r][lane] + qsf[1][r][lane] + qsf[2][r][lane] + bb;
            out2[(m0 + rbase + r) * NFEAT + n0 + col] = fmaxf(v, 0.f);
        }
    }
}

// ---------------------------------------------------------------------------
extern "C" void kernel_launch(void* const* d_in, const int* in_sizes, int n_in,
                              void* d_out, int out_size, void* d_ws, size_t ws_size,
                              hipStream_t stream) {
    (void)in_sizes; (void)n_in; (void)out_size; (void)ws_size;
    const float* vf      = (const float*)d_in[3];
    const float* sen_fea = (const float*)d_in[4];
    const float* loc     = (const float*)d_in[5];
    const int*   vmask   = (const int*)d_in[7];
    const float* W1 = (const float*)d_in[8];
    const float* b1 = (const float*)d_in[9];
    const float* W2 = (const float*)d_in[10];
    const float* b2 = (const float*)d_in[11];
    const float* W3 = (const float*)d_in[12];
    const float* b3 = (const float*)d_in[13];
    const float* W4 = (const float*)d_in[14];
    const float* b4 = (const float*)d_in[15];

    float* out0 = (float*)d_out;
    float* out1 = out0 + (size_t)BS * T * D;
    float* out2 = out1 + (size_t)BS * D;

    char* w = (char*)d_ws;
    float* pgv  = (float*)(w);                         // 4 MB
    float* pseg = (float*)(w + (4 << 20));             // 4 MB
    u16*   cat  = (u16*)  (w + (8 << 20));             // 688128 B
    u16*   W1b  = (u16*)  (w + (9 << 20));             // 1 MB
    u16*   W2b  = (u16*)  (w + (10 << 20));            // 1 MB
    u16*   W4b  = (u16*)  (w + (11 << 20));            // 5.25 MB

    ka<<<1024, 256, 0, stream>>>(vf, out0, vmask, loc, W1, W2, W4,
                                 W1b, W2b, W4b, pgv, pseg);
    kB<<<256, 256, 0, stream>>>(sen_fea, loc, W3, b3, vmask, pgv, pseg,
                                W1b, b1, W2b, b2, cat, out1);
    kD<<<512, 256, 0, stream>>>(cat, W4b, b4, out2);
}

// Round 9
// 103.300 us; speedup vs baseline: 1.0666x; 1.0666x over previous
//
#include <hip/hip_runtime.h>
#include <hip/hip_bf16.h>

#define BS 128
#define T 256
#define D 1024
#define NCAT 2688
#define NFEAT 1024

typedef short bf16x8 __attribute__((ext_vector_type(8)));
typedef float f32x4 __attribute__((ext_vector_type(4)));
typedef unsigned short u16;
typedef u16 u16x4 __attribute__((ext_vector_type(4)));

__device__ __forceinline__ u16 f2bf(float f) {
    unsigned int u = __float_as_uint(f);
    u += 0x7fffu + ((u >> 16) & 1u);   // round-to-nearest-even
    return (u16)(u >> 16);
}
__device__ __forceinline__ short fb(float x) {   // same RNE via hw cvt
    __hip_bfloat16 h = __float2bfloat16(x);
    union { __hip_bfloat16 h; short s; } u; u.h = h; return u.s;
}

// ctl ints: [0..127] vlen, [128..255] s, [256..383] e  (written by ka, read by kB)

// ---------------------------------------------------------------------------
// ka: blocks [0,1024): copy+pool (b,tc) — R3-proven streaming form; tc==0
//       block also stores vlen/s/e scalars.
//     blocks [1024,4736): f32->bf16 convert of W1,W2,W4 (backfill the stream).
//     blocks [4736,4864): zero-dep tail: sen->cat(bf16)+out1(f32), loc head.
// cat layout: [sen 0..1023 | gv 1024..2047 | vs 2048..2559 | loc 2560..2687]
// ---------------------------------------------------------------------------
__global__ __launch_bounds__(256, 4)
void ka(const float* __restrict__ vf, float* __restrict__ out0,
        const int* __restrict__ vmask, const float* __restrict__ loc,
        const float* __restrict__ sen_fea,
        const float* __restrict__ W1, const float* __restrict__ W2,
        const float* __restrict__ W3, const float* __restrict__ W4,
        const float* __restrict__ b3,
        u16* __restrict__ W1b, u16* __restrict__ W2b, u16* __restrict__ W4b,
        float* __restrict__ pgv, float* __restrict__ pseg,
        u16* __restrict__ cat, float* __restrict__ out1,
        int* __restrict__ ctl) {
    int blk = blockIdx.x, tid = threadIdx.x;

    if (blk >= 4736) {                       // ---- zero-dep tail role ----
        int b = blk - 4736;
        int d0 = tid * 4;
        f32x4 sf = *(const f32x4*)(sen_fea + b * D + d0);
        *(f32x4*)(out1 + b * D + d0) = sf;
        u16x4 sb;
        sb[0] = f2bf(sf[0]); sb[1] = f2bf(sf[1]); sb[2] = f2bf(sf[2]); sb[3] = f2bf(sf[3]);
        *(u16x4*)(cat + b * NCAT + d0) = sb;
        if (tid < 128) {
            float v = loc[2 * b] * W3[2 * tid] + loc[2 * b + 1] * W3[2 * tid + 1] + b3[tid];
            cat[b * NCAT + 2560 + tid] = f2bf(fmaxf(v, 0.f));
        }
        return;
    }

    if (blk >= 1024) {                       // ---- weight conversion ----
        int i = (blk - 1024) * 256 + tid;    // float4 index, 950272 total
        const float* src; u16* dst;
        if (i < 131072)      { src = W1 + 4 * i;            dst = W1b + 4 * i; }
        else if (i < 262144) { src = W2 + 4 * (i - 131072); dst = W2b + 4 * (i - 131072); }
        else                 { src = W4 + 4 * (i - 262144); dst = W4b + 4 * (i - 262144); }
        f32x4 v = *(const f32x4*)src;
        u16x4 o;
        o[0] = f2bf(v[0]); o[1] = f2bf(v[1]); o[2] = f2bf(v[2]); o[3] = f2bf(v[3]);
        *(u16x4*)dst = o;
        return;
    }

    // ---- copy + pool (R3-proven) ----
    int b = blk >> 3, tc = blk & 7;
    __shared__ int red[256];
    __shared__ int sse[3];
    red[tid] = vmask[b * T + tid];
    __syncthreads();
    for (int off = 128; off > 0; off >>= 1) {
        if (tid < off) red[tid] += red[tid + off];
        __syncthreads();
    }
    if (tid == 0) {
        int vl = red[0];
        float sc = (float)(vl - 1);
        sse[0] = vl;
        sse[1] = (int)floorf(loc[2 * b] * sc);
        sse[2] = (int)floorf(loc[2 * b + 1] * sc);
    }
    __syncthreads();
    int vl = sse[0], s = sse[1], e = sse[2];
    if (tc == 0 && tid == 0) {
        ctl[b] = vl; ctl[128 + b] = s; ctl[256 + b] = e;
    }

    int t0 = tc * 32;
    int d0 = tid * 4;
    f32x4 g  = {0.f, 0.f, 0.f, 0.f};
    f32x4 sg = {0.f, 0.f, 0.f, 0.f};
    const float* src = vf   + ((size_t)(b * T + t0)) * D + d0;
    float*       dst = out0 + ((size_t)(b * T + t0)) * D + d0;
    for (int i = 0; i < 32; ++i) {           // fixed bound -> unrolled, deep MLP
        f32x4 v = *(const f32x4*)src;
        __builtin_nontemporal_store(v, (f32x4*)dst);
        int t = t0 + i;
        if (t < vl) g += v;
        if (t >= s && t <= e) sg += v;
        src += D; dst += D;
    }
    int o = (b * 8 + tc) * D + d0;
    *(f32x4*)(pgv  + o) = g;
    *(f32x4*)(pseg + o) = sg;
}

// ---------------------------------------------------------------------------
// kB: ONE launch, two independent roles (k2 eliminated):
//  blocks [0,128): k3' — vs = relu((lv@W1^T+b1)*(sen@W2^T+b2)) -> cat[vs].
//    (mt,ntg): 16 rows x 32 cols. 4 waves: sub=wid&1 -> 16-col subtile;
//    chain=wid>>1: chain0 = P (A = on-the-fly reduce of 8 pseg chunks x
//    lvscale, cvt to bf16 — bit-identical to old k2+k3), chain1 = Q (bf16
//    sen from cat). LDS exchange, chain0 writes.
//  blocks [128,256): gv finalize — reduce pgv (c=0..7 order) -> cat[gv].
// ---------------------------------------------------------------------------
__global__ void kB(const float* __restrict__ pgv, const float* __restrict__ pseg,
                   const u16* __restrict__ W1b, const float* __restrict__ b1,
                   const u16* __restrict__ W2b, const float* __restrict__ b2,
                   const int* __restrict__ ctl, u16* __restrict__ cat) {
    int blk = blockIdx.x, tid = threadIdx.x;

    if (blk >= 128) {
        // ---------------- gv finalize ----------------
        int b = blk - 128;
        float inv_vl = 1.0f / (float)ctl[b];
        int d0 = tid * 4;
        f32x4 gs = {0.f, 0.f, 0.f, 0.f};
#pragma unroll
        for (int c = 0; c < 8; ++c) gs += *(const f32x4*)(pgv + (b * 8 + c) * D + d0);
        u16x4 o;
        o[0] = f2bf(gs[0] * inv_vl); o[1] = f2bf(gs[1] * inv_vl);
        o[2] = f2bf(gs[2] * inv_vl); o[3] = f2bf(gs[3] * inv_vl);
        *(u16x4*)(cat + b * NCAT + 1024 + d0) = o;
        return;
    }

    // ---------------- k3' ----------------
    int mt = blk >> 4, ntg = blk & 15;       // 8 m-tiles x 16 col-groups of 32
    int m0 = mt * 16;
    int wid = tid >> 6, lane = tid & 63;
    int sub = wid & 1, chain = wid >> 1;
    int n0 = ntg * 32 + sub * 16;
    int row = lane & 15, kg = lane >> 4;

    __shared__ float qs[2][4][64];
    f32x4 acc = {0.f, 0.f, 0.f, 0.f};
    int col = lane & 15, rbase = (lane >> 4) * 4;

    if (chain == 0) {
        // P: A = (sum_c pseg_c) * lvscale, cvt8 -> MFMA with W1b
        int bb = m0 + row;
        int vl = ctl[bb], s = ctl[128 + bb], e = ctl[256 + bb];
        int cnt = e + 1 - s; if (cnt < 1) cnt = 1;
        float lvs = (s <= e) ? (1.0f / (float)cnt) : 0.f;

        const float* paP = pseg + (size_t)(bb * 8) * D + kg * 8;
        const u16*  pbP = W1b + (n0 + row) * D + kg * 8;
        for (int k = 0; k < 1024; k += 32) {
            const float* pk = paP + k;
            f32x4 alo = {0.f, 0.f, 0.f, 0.f}, ahi = {0.f, 0.f, 0.f, 0.f};
#pragma unroll
            for (int c = 0; c < 8; ++c) {
                alo += *(const f32x4*)(pk + c * D);
                ahi += *(const f32x4*)(pk + c * D + 4);
            }
            alo *= lvs; ahi *= lvs;
            bf16x8 af;
            af[0] = fb(alo[0]); af[1] = fb(alo[1]); af[2] = fb(alo[2]); af[3] = fb(alo[3]);
            af[4] = fb(ahi[0]); af[5] = fb(ahi[1]); af[6] = fb(ahi[2]); af[7] = fb(ahi[3]);
            acc = __builtin_amdgcn_mfma_f32_16x16x32_bf16(af, *(const bf16x8*)(pbP + k),
                                                          acc, 0, 0, 0);
        }
    } else {
        // Q: A = sen bf16 (cat cols 0..1023), B = W2b
        const u16* paQ = cat + (m0 + row) * NCAT + kg * 8;
        const u16* pbQ = W2b + (n0 + row) * D + kg * 8;
        for (int k = 0; k < 1024; k += 32)
            acc = __builtin_amdgcn_mfma_f32_16x16x32_bf16(*(const bf16x8*)(paQ + k),
                                                          *(const bf16x8*)(pbQ + k),
                                                          acc, 0, 0, 0);
        float bb2 = b2[n0 + col];
#pragma unroll
        for (int r = 0; r < 4; ++r) qs[sub][r][lane] = acc[r] + bb2;
    }
    __syncthreads();
    if (chain == 0) {
        float bb1 = b1[n0 + col];
#pragma unroll
        for (int r = 0; r < 4; ++r) {
            float P = acc[r] + bb1;
            cat[(m0 + rbase + r) * NCAT + 2048 + n0 + col] =
                f2bf(fmaxf(P * qs[sub][r][lane], 0.f));
        }
    }
}

// ---------------------------------------------------------------------------
// kD: k4 feature GEMM — out2 = relu(cat @ W4^T + b4). M=128,N=1024,K=2688.
// 512 blocks x 4 waves, split-K=4 (672 each), LDS reduce. (R3-proven)
// ---------------------------------------------------------------------------
__global__ void kD(const u16* __restrict__ cat, const u16* __restrict__ W4b,
                   const float* __restrict__ b4, float* __restrict__ out2) {
    int blk = blockIdx.x, tid = threadIdx.x;
    __shared__ float qsf[3][4][64];

    int mt = blk >> 6, nt = blk & 63;
    int wid = tid >> 6, lane = tid & 63;
    int m0 = mt * 16, n0 = nt * 16;
    int row = lane & 15, kg = lane >> 4;

    const u16* pa = cat + (m0 + row) * NCAT + wid * 672 + kg * 8;
    const u16* pb = W4b + (n0 + row) * NCAT + wid * 672 + kg * 8;

    f32x4 acc = {0.f, 0.f, 0.f, 0.f};
    for (int k = 0; k < 672; k += 32)
        acc = __builtin_amdgcn_mfma_f32_16x16x32_bf16(*(const bf16x8*)(pa + k),
                                                      *(const bf16x8*)(pb + k), acc, 0, 0, 0);
    int col = lane & 15, rbase = (lane >> 4) * 4;
    if (wid) {
#pragma unroll
        for (int r = 0; r < 4; ++r) qsf[wid - 1][r][lane] = acc[r];
    }
    __syncthreads();
    if (wid == 0) {
        float bb = b4[n0 + col];
#pragma unroll
        for (int r = 0; r < 4; ++r) {
            float v = acc[r] + qsf[0][r][lane] + qsf[1][r][lane] + qsf[2][r][lane] + bb;
            out2[(m0 + rbase + r) * NFEAT + n0 + col] = fmaxf(v, 0.f);
        }
    }
}

// ---------------------------------------------------------------------------
extern "C" void kernel_launch(void* const* d_in, const int* in_sizes, int n_in,
                              void* d_out, int out_size, void* d_ws, size_t ws_size,
                              hipStream_t stream) {
    (void)in_sizes; (void)n_in; (void)out_size; (void)ws_size;
    const float* vf      = (const float*)d_in[3];
    const float* sen_fea = (const float*)d_in[4];
    const float* loc     = (const float*)d_in[5];
    const int*   vmask   = (const int*)d_in[7];
    const float* W1 = (const float*)d_in[8];
    const float* b1 = (const float*)d_in[9];
    const float* W2 = (const float*)d_in[10];
    const float* b2 = (const float*)d_in[11];
    const float* W3 = (const float*)d_in[12];
    const float* b3 = (const float*)d_in[13];
    const float* W4 = (const float*)d_in[14];
    const float* b4 = (const float*)d_in[15];

    float* out0 = (float*)d_out;
    float* out1 = out0 + (size_t)BS * T * D;
    float* out2 = out1 + (size_t)BS * D;

    char* w = (char*)d_ws;
    float* pgv  = (float*)(w);                         // 4 MB
    float* pseg = (float*)(w + (4 << 20));             // 4 MB
    u16*   cat  = (u16*)  (w + (8 << 20));             // 688128 B
    u16*   W1b  = (u16*)  (w + (9 << 20));             // 1 MB
    u16*   W2b  = (u16*)  (w + (10 << 20));            // 1 MB
    u16*   W4b  = (u16*)  (w + (11 << 20));            // 5.25 MB
    int*   ctl  = (int*)  (w + (17 << 20));            // 384 ints

    ka<<<4864, 256, 0, stream>>>(vf, out0, vmask, loc, sen_fea,
                                 W1, W2, W3, W4, b3,
                                 W1b, W2b, W4b, pgv, pseg, cat, out1, ctl);
    kB<<<256, 256, 0, stream>>>(pgv, pseg, W1b, b1, W2b, b2, ctl, cat);
    kD<<<512, 256, 0, stream>>>(cat, W4b, b4, out2);
}

// Round 10
// 74.506 us; speedup vs baseline: 1.4787x; 1.3865x over previous
//
#include <hip/hip_runtime.h>

#define BS 128
#define T 256
#define D 1024
#define NCAT 2688
#define NFEAT 1024

typedef short bf16x8 __attribute__((ext_vector_type(8)));
typedef float f32x4 __attribute__((ext_vector_type(4)));
typedef unsigned short u16;
typedef u16 u16x4 __attribute__((ext_vector_type(4)));

__device__ __forceinline__ u16 f2bf(float f) {
    unsigned int u = __float_as_uint(f);
    u += 0x7fffu + ((u >> 16) & 1u);   // round-to-nearest-even
    return (u16)(u >> 16);
}

// ---------------------------------------------------------------------------
// ka: blocks [0,1024): copy+pool (b,tc) — R3-proven streaming form.
//     blocks [1024,4736): f32->bf16 convert of W1,W2,W4 (backfill).
//     blocks [4736,4864): zero-dep tail: sen->cat(bf16)+out1(f32), loc head.
// cat layout: [sen 0..1023 | gv 1024..2047 | vs 2048..2559 | loc 2560..2687]
// ---------------------------------------------------------------------------
__global__ __launch_bounds__(256, 4)
void ka(const float* __restrict__ vf, float* __restrict__ out0,
        const int* __restrict__ vmask, const float* __restrict__ loc,
        const float* __restrict__ sen_fea,
        const float* __restrict__ W1, const float* __restrict__ W2,
        const float* __restrict__ W3, const float* __restrict__ W4,
        const float* __restrict__ b3,
        u16* __restrict__ W1b, u16* __restrict__ W2b, u16* __restrict__ W4b,
        float* __restrict__ pgv, float* __restrict__ pseg,
        u16* __restrict__ cat, float* __restrict__ out1) {
    int blk = blockIdx.x, tid = threadIdx.x;

    if (blk >= 4736) {                       // ---- zero-dep tail role ----
        int b = blk - 4736;
        int d0 = tid * 4;
        f32x4 sf = *(const f32x4*)(sen_fea + b * D + d0);
        *(f32x4*)(out1 + b * D + d0) = sf;
        u16x4 sb;
        sb[0] = f2bf(sf[0]); sb[1] = f2bf(sf[1]); sb[2] = f2bf(sf[2]); sb[3] = f2bf(sf[3]);
        *(u16x4*)(cat + b * NCAT + d0) = sb;
        if (tid < 128) {
            float v = loc[2 * b] * W3[2 * tid] + loc[2 * b + 1] * W3[2 * tid + 1] + b3[tid];
            cat[b * NCAT + 2560 + tid] = f2bf(fmaxf(v, 0.f));
        }
        return;
    }

    if (blk >= 1024) {                       // ---- weight conversion ----
        int i = (blk - 1024) * 256 + tid;    // float4 index, 950272 total
        const float* src; u16* dst;
        if (i < 131072)      { src = W1 + 4 * i;            dst = W1b + 4 * i; }
        else if (i < 262144) { src = W2 + 4 * (i - 131072); dst = W2b + 4 * (i - 131072); }
        else                 { src = W4 + 4 * (i - 262144); dst = W4b + 4 * (i - 262144); }
        f32x4 v = *(const f32x4*)src;
        u16x4 o;
        o[0] = f2bf(v[0]); o[1] = f2bf(v[1]); o[2] = f2bf(v[2]); o[3] = f2bf(v[3]);
        *(u16x4*)dst = o;
        return;
    }

    // ---- copy + pool (R3-proven, fixed 32-iter loop) ----
    int b = blk >> 3, tc = blk & 7;
    __shared__ int red[256];
    __shared__ int sse[3];
    red[tid] = vmask[b * T + tid];
    __syncthreads();
    for (int off = 128; off > 0; off >>= 1) {
        if (tid < off) red[tid] += red[tid + off];
        __syncthreads();
    }
    if (tid == 0) {
        int vl = red[0];
        float sc = (float)(vl - 1);
        sse[0] = vl;
        sse[1] = (int)floorf(loc[2 * b] * sc);
        sse[2] = (int)floorf(loc[2 * b + 1] * sc);
    }
    __syncthreads();
    int vl = sse[0], s = sse[1], e = sse[2];

    int t0 = tc * 32;
    int d0 = tid * 4;
    f32x4 g  = {0.f, 0.f, 0.f, 0.f};
    f32x4 sg = {0.f, 0.f, 0.f, 0.f};
    const float* src = vf   + ((size_t)(b * T + t0)) * D + d0;
    float*       dst = out0 + ((size_t)(b * T + t0)) * D + d0;
    for (int i = 0; i < 32; ++i) {
        f32x4 v = *(const f32x4*)src;
        __builtin_nontemporal_store(v, (f32x4*)dst);
        int t = t0 + i;
        if (t < vl) g += v;
        if (t >= s && t <= e) sg += v;
        src += D; dst += D;
    }
    int o = (b * 8 + tc) * D + d0;
    *(f32x4*)(pgv  + o) = g;
    *(f32x4*)(pseg + o) = sg;
}

// ---------------------------------------------------------------------------
// k2': gv + lv finalize only (sen/loc moved to ka). 128 blocks x 256.
// ---------------------------------------------------------------------------
__global__ void k2p(const float* __restrict__ loc, const int* __restrict__ vmask,
                    const float* __restrict__ pgv, const float* __restrict__ pseg,
                    u16* __restrict__ lv_bf, u16* __restrict__ cat) {
    int b = blockIdx.x, tid = threadIdx.x;
    __shared__ int red[256];
    __shared__ int sse[3];
    red[tid] = vmask[b * T + tid];
    __syncthreads();
    for (int off = 128; off > 0; off >>= 1) {
        if (tid < off) red[tid] += red[tid + off];
        __syncthreads();
    }
    if (tid == 0) {
        int vl = red[0];
        float sc = (float)(vl - 1);
        sse[0] = vl;
        sse[1] = (int)floorf(loc[2 * b] * sc);
        sse[2] = (int)floorf(loc[2 * b + 1] * sc);
    }
    __syncthreads();
    int vl = sse[0], s = sse[1], e = sse[2];
    float inv_vl = 1.0f / (float)vl;
    int cnt = e + 1 - s; if (cnt < 1) cnt = 1;
    float inv_cnt = 1.0f / (float)cnt;
    bool valid = (s <= e);

    for (int d = tid; d < D; d += 256) {
        float gs = 0.f, ss = 0.f;
#pragma unroll
        for (int c = 0; c < 8; ++c) {
            gs += pgv [(b * 8 + c) * D + d];
            ss += pseg[(b * 8 + c) * D + d];
        }
        cat[b * NCAT + 1024 + d] = f2bf(gs * inv_vl);
        lv_bf[b * D + d] = f2bf(valid ? ss * inv_cnt : 0.f);
    }
}

// ---------------------------------------------------------------------------
// kBC: ONE launch, two independent roles (disjoint cat columns -> no race):
//  blocks [0,128): k3 — vs = relu((lv@W1^T+b1)*(sen@W2^T+b2)) -> cat[vs].
//    (R7-kC proven form: sub = tid>>7, chain = (tid>>6)&1.)
//  blocks [128,640): k4a — partial feature GEMM over K in [0,2048)u[2560,2688)
//    (2176 cols; NO vs dependency), split-K=4, LDS reduce, f32 partial -> part.
// ---------------------------------------------------------------------------
__global__ void kBC(const u16* __restrict__ lv, const u16* __restrict__ cat_ro,
                    const u16* __restrict__ W1b, const float* __restrict__ b1,
                    const u16* __restrict__ W2b, const float* __restrict__ b2,
                    const u16* __restrict__ W4b, u16* __restrict__ cat,
                    float* __restrict__ part) {
    int blk = blockIdx.x, tid = threadIdx.x;

    if (blk < 128) {
        // ---------------- k3 ----------------
        __shared__ float qs[2][4][64];
        int mt = blk >> 4, ntg = blk & 15;
        int sub = tid >> 7, chain = (tid >> 6) & 1, lane = tid & 63;
        int m0 = mt * 16, n0 = ntg * 32 + sub * 16;
        int row = lane & 15, kg = lane >> 4;

        const u16* pa = chain ? (cat_ro + (m0 + row) * NCAT + kg * 8)   // sen
                              : (lv     + (m0 + row) * D    + kg * 8);
        const u16* pb = (chain ? W2b : W1b) + (n0 + row) * D + kg * 8;

        f32x4 acc = {0.f, 0.f, 0.f, 0.f};
        for (int k = 0; k < 1024; k += 32)
            acc = __builtin_amdgcn_mfma_f32_16x16x32_bf16(*(const bf16x8*)(pa + k),
                                                          *(const bf16x8*)(pb + k),
                                                          acc, 0, 0, 0);
        int col = lane & 15, rbase = (lane >> 4) * 4;
        float bb = (chain ? b2 : b1)[n0 + col];
        if (chain) {
#pragma unroll
            for (int r = 0; r < 4; ++r) qs[sub][r][lane] = acc[r] + bb;
        }
        __syncthreads();
        if (!chain) {
#pragma unroll
            for (int r = 0; r < 4; ++r) {
                float p = acc[r] + bb;
                cat[(m0 + rbase + r) * NCAT + 2048 + n0 + col] =
                    f2bf(fmaxf(p * qs[sub][r][lane], 0.f));
            }
        }
        return;
    }

    // ---------------- k4a: partial K (skip vs columns) ----------------
    __shared__ float qsf[3][4][64];
    int bi = blk - 128;                      // [0,512)
    int mt = bi >> 6, nt = bi & 63;
    int wid = tid >> 6, lane = tid & 63;
    int m0 = mt * 16, n0 = nt * 16;
    int row = lane & 15, kg = lane >> 4;

    const u16* pa = cat_ro + (m0 + row) * NCAT + kg * 8;
    const u16* pb = W4b    + (n0 + row) * NCAT + kg * 8;

    f32x4 acc = {0.f, 0.f, 0.f, 0.f};
    for (int k = 0; k < 544; k += 32) {      // 17 chunks per wave; fixed bound
        int ccol = wid * 544 + k;            // virtual col in [0,2176)
        int acol = ccol + (ccol >= 2048 ? 512 : 0);   // skip vs [2048,2560)
        acc = __builtin_amdgcn_mfma_f32_16x16x32_bf16(*(const bf16x8*)(pa + acol),
                                                      *(const bf16x8*)(pb + acol),
                                                      acc, 0, 0, 0);
    }
    int lane64 = lane;
    if (wid) {
#pragma unroll
        for (int r = 0; r < 4; ++r) qsf[wid - 1][r][lane64] = acc[r];
    }
    __syncthreads();
    if (wid == 0) {
#pragma unroll
        for (int r = 0; r < 4; ++r)
            part[bi * 256 + r * 64 + lane64] =
                acc[r] + qsf[0][r][lane64] + qsf[1][r][lane64] + qsf[2][r][lane64];
    }
}

// ---------------------------------------------------------------------------
// k4b: finish feature GEMM — vs columns (K=512) + stored partial + bias, relu.
// 512 blocks x 128 thr: 2 waves x K=256 (8 MFMA), LDS swap, wave0 writes.
// ---------------------------------------------------------------------------
__global__ void k4b(const u16* __restrict__ cat, const u16* __restrict__ W4b,
                    const float* __restrict__ b4, const float* __restrict__ part,
                    float* __restrict__ out2) {
    int blk = blockIdx.x, tid = threadIdx.x;
    __shared__ float qs[4][64];

    int mt = blk >> 6, nt = blk & 63;
    int wid = tid >> 6, lane = tid & 63;
    int m0 = mt * 16, n0 = nt * 16;
    int row = lane & 15, kg = lane >> 4;

    const u16* pa = cat + (m0 + row) * NCAT + 2048 + wid * 256 + kg * 8;
    const u16* pb = W4b + (n0 + row) * NCAT + 2048 + wid * 256 + kg * 8;

    f32x4 acc = {0.f, 0.f, 0.f, 0.f};
    for (int k = 0; k < 256; k += 32)
        acc = __builtin_amdgcn_mfma_f32_16x16x32_bf16(*(const bf16x8*)(pa + k),
                                                      *(const bf16x8*)(pb + k),
                                                      acc, 0, 0, 0);
    int col = lane & 15, rbase = (lane >> 4) * 4;
    if (wid == 1) {
#pragma unroll
        for (int r = 0; r < 4; ++r) qs[r][lane] = acc[r];
    }
    __syncthreads();
    if (wid == 0) {
        float bb = b4[n0 + col];
#pragma unroll
        for (int r = 0; r < 4; ++r) {
            float v = acc[r] + qs[r][lane] + part[blk * 256 + r * 64 + lane] + bb;
            out2[(m0 + rbase + r) * NFEAT + n0 + col] = fmaxf(v, 0.f);
        }
    }
}

// ---------------------------------------------------------------------------
extern "C" void kernel_launch(void* const* d_in, const int* in_sizes, int n_in,
                              void* d_out, int out_size, void* d_ws, size_t ws_size,
                              hipStream_t stream) {
    (void)in_sizes; (void)n_in; (void)out_size; (void)ws_size;
    const float* vf      = (const float*)d_in[3];
    const float* sen_fea = (const float*)d_in[4];
    const float* loc     = (const float*)d_in[5];
    const int*   vmask   = (const int*)d_in[7];
    const float* W1 = (const float*)d_in[8];
    const float* b1 = (const float*)d_in[9];
    const float* W2 = (const float*)d_in[10];
    const float* b2 = (const float*)d_in[11];
    const float* W3 = (const float*)d_in[12];
    const float* b3 = (const float*)d_in[13];
    const float* W4 = (const float*)d_in[14];
    const float* b4 = (const float*)d_in[15];

    float* out0 = (float*)d_out;
    float* out1 = out0 + (size_t)BS * T * D;
    float* out2 = out1 + (size_t)BS * D;

    char* w = (char*)d_ws;
    float* pgv  = (float*)(w);                         // 4 MB
    float* pseg = (float*)(w + (4 << 20));             // 4 MB
    u16*   cat  = (u16*)  (w + (8 << 20));             // 688128 B
    u16*   W1b  = (u16*)  (w + (9 << 20));             // 1 MB
    u16*   W2b  = (u16*)  (w + (10 << 20));            // 1 MB
    u16*   W4b  = (u16*)  (w + (11 << 20));            // 5.25 MB
    float* part = (float*)(w + (17 << 20));            // 512 KB
    u16*   lv   = (u16*)  (w + (18 << 20));            // 256 KB

    ka<<<4864, 256, 0, stream>>>(vf, out0, vmask, loc, sen_fea,
                                 W1, W2, W3, W4, b3,
                                 W1b, W2b, W4b, pgv, pseg, cat, out1);
    k2p<<<128, 256, 0, stream>>>(loc, vmask, pgv, pseg, lv, cat);
    kBC<<<640, 256, 0, stream>>>(lv, cat, W1b, b1, W2b, b2, W4b, cat, part);
    k4b<<<512, 128, 0, stream>>>(cat, W4b, b4, part, out2);
}